// Round 17
// baseline (425.944 us; speedup 1.0000x reference)
//
#include <hip/hip_runtime.h>
#include <hip/hip_bf16.h>

typedef __bf16 bf16_t;
typedef bf16_t bf16x8 __attribute__((ext_vector_type(8)));
typedef bf16_t bf16x4v __attribute__((ext_vector_type(4)));
typedef float f32x4 __attribute__((ext_vector_type(4)));
typedef unsigned u32x4 __attribute__((ext_vector_type(4)));

// problem constants
static constexpr int EE = 1024;   // E
static constexpr int SS = 2048;   // S
static constexpr int DK = 64;
static constexpr float QSCALE = 0.125f * 1.44269504f;

__device__ __forceinline__ void gload_lds16(const void* g, void* l) {
  __builtin_amdgcn_global_load_lds(
      (__attribute__((address_space(1))) void*)g,
      (__attribute__((address_space(3))) void*)l, 16, 0, 0);
}

__device__ __forceinline__ f32x4 mfma16(bf16x8 a, bf16x8 b, f32x4 c) {
  return __builtin_amdgcn_mfma_f32_16x16x32_bf16(a, b, c, 0, 0, 0);
}

template<int OFF>
__device__ __forceinline__ bf16x4v tr8(unsigned va) {
  bf16x4v d;
  asm volatile("ds_read_b64_tr_b16 %0, %1 offset:%c2"
               : "=v"(d) : "v"(va), "i"(OFF));
  return d;
}

// ---------------------------------------------------------------------------
// prep: x -> bf16, and qh = cos(x + theta) into A2 right half.
// ---------------------------------------------------------------------------
__global__ void __launch_bounds__(256) prep_x_kernel(
    const float* __restrict__ x, const float* __restrict__ theta,
    bf16_t* __restrict__ xbf, bf16_t* __restrict__ A2)
{
  const long t = (long)blockIdx.x * 256 + threadIdx.x;
  const long e0 = t * 8;
  const int col = (int)(e0 & (EE - 1));
  const long row = e0 >> 10;
  const float4 v0 = *(const float4*)&x[e0];
  const float4 v1 = *(const float4*)&x[e0 + 4];
  float xs[8] = {v0.x, v0.y, v0.z, v0.w, v1.x, v1.y, v1.z, v1.w};
  const int d0 = col & (DK - 1);
  bf16x8 xb, qb;
#pragma unroll
  for (int j = 0; j < 8; ++j) {
    xb[j] = (bf16_t)xs[j];
    qb[j] = (bf16_t)__cosf(xs[j] + theta[d0 + j]);
  }
  *(bf16x8*)&xbf[e0] = xb;
  *(bf16x8*)&A2[row * 2048 + EE + col] = qb;
}

// ---------------------------------------------------------------------------
// fused weight transpose + f32->bf16 for ALL seven weights in ONE launch.
// ---------------------------------------------------------------------------
__global__ void __launch_bounds__(256) transpose_all_kernel(
    const float* __restrict__ Wq, const float* __restrict__ Wk,
    const float* __restrict__ Wv, const float* __restrict__ Wo,
    const float* __restrict__ Wcq, const float* __restrict__ W1,
    const float* __restrict__ W2,
    bf16_t* __restrict__ BtQKV, bf16_t* __restrict__ Bt2,
    bf16_t* __restrict__ BtW1, bf16_t* __restrict__ BtW2)
{
  const int bid = blockIdx.x;
  const float* src; bf16_t* dst; int N; long dstride, dcol0; int bx, by;
  if (bid < 5120) {
    const int seg = bid >> 10, r = bid & 1023;
    bx = r & 31; by = r >> 5; N = 1024;
    if      (seg == 0) { src = Wq;  dst = BtQKV;               dstride = 1024; dcol0 = 0; }
    else if (seg == 1) { src = Wk;  dst = BtQKV + 1024 * 1024; dstride = 1024; dcol0 = 0; }
    else if (seg == 2) { src = Wv;  dst = BtQKV + 2048 * 1024; dstride = 1024; dcol0 = 0; }
    else if (seg == 3) { src = Wo;  dst = Bt2;                 dstride = 2048; dcol0 = 0; }
    else               { src = Wcq; dst = Bt2;                 dstride = 2048; dcol0 = 1024; }
  } else if (bid < 9216) {
    const int r = bid - 5120;
    src = W1; dst = BtW1; N = 4096; dstride = 1024; dcol0 = 0;
    bx = r & 127; by = r >> 7;
  } else {
    const int r = bid - 9216;
    src = W2; dst = BtW2; N = 1024; dstride = 4096; dcol0 = 0;
    bx = r & 31; by = r >> 5;
  }
  __shared__ float tile[32][33];
  const int tx = threadIdx.x, ty = threadIdx.y;
  const long n0 = (long)bx * 32, k0 = (long)by * 32;
#pragma unroll
  for (int j = 0; j < 4; ++j)
    tile[ty + j * 8][tx] = src[(k0 + ty + j * 8) * N + n0 + tx];
  __syncthreads();
#pragma unroll
  for (int j = 0; j < 4; ++j)
    dst[(n0 + ty + j * 8) * dstride + dcol0 + k0 + tx] = (bf16_t)tile[tx][ty + j * 8];
}

// ---------------------------------------------------------------------------
// gemm8p v3 — 8-phase GEMM templated on TN (round-16 v2 skeleton, proven).
// TN=256: 8 waves 2Mx4N, per-wave 128x64, acc[8][4] (identical to v2).
// TN=128: 8 waves 4Mx2N, per-wave 64x64, acc[4][4]; B halves 64x64 (1 gload
//   each, staged together in ph2); A staging identical (A is 256x64 both).
// BK=64, 2-buf LDS; reads in PRE-barrier region (the r16 fix); stage
// schedule ph0=A-h0(t+1) ph1=A-h1(t+1) ph2=B(t+1) [TN=128] or
// ph0=A both / ph1=B both [TN=256]; single vmcnt(0) in ph3.
// Publish/WAR ledger verified for both TN (quadrant reads of the same half
// are covered: half published by ph3 drain of t-1; overwrite >=2 barriers
// after the half's last read).
// Swizzle: 16B slot ^= row&7 at pre-swizzled SOURCE and at ds_read.
// MODE 0: QKV (QSCALE on cols<1024) / 1: 0.5*acc+res / 2: relu+bias /
// MODE 3: acc+bias+res. All bf16 outputs.
// ---------------------------------------------------------------------------
#define GP_BAR __builtin_amdgcn_s_barrier()
#define GP_LG0 asm volatile("s_waitcnt lgkmcnt(0)" ::: "memory")
#define GP_VM0 asm volatile("s_waitcnt vmcnt(0)" ::: "memory")
#define GP_SCB __builtin_amdgcn_sched_barrier(0)
#define GP_P1 __builtin_amdgcn_s_setprio(1)
#define GP_P0 __builtin_amdgcn_s_setprio(0)

template<int MODE, int TN>
__global__ void __launch_bounds__(512, 2) gemm8p(
    const bf16_t* __restrict__ A, const bf16_t* __restrict__ Bt,
    void* __restrict__ C, int M, int N, int K,
    const float* __restrict__ aux1, const bf16_t* __restrict__ aux2)
{
  constexpr int MBQ = (TN == 256) ? 4 : 2;     // m-frags per quadrant
  __shared__ bf16_t AsF[32768];
  __shared__ bf16_t BsF[(TN == 256) ? 32768 : 16384];
  const int tid = threadIdx.x;
  const int lane = tid & 63, wid = tid >> 6;
  const int wr = (TN == 256) ? (wid >> 2) : (wid >> 1);
  const int wc = (TN == 256) ? (wid & 3) : (wid & 1);
  const int lr = lane & 15, lk = lane >> 4;
  const int gx = gridDim.x;
  const int nwg = gx * gridDim.y;
  const int bid = blockIdx.y * gx + blockIdx.x;
  const int swz = (bid & 7) * (nwg >> 3) + (bid >> 3);   // nwg % 8 == 0
  const long m0 = (long)(swz / gx) * 256;
  const long n0 = (long)(swz % gx) * TN;

  // staging: thread owns 16B slot (tid&7) of row (tid>>3); source col
  // pre-swizzled slot^=(row&7); LDS dest linear.
  const int strow = tid >> 3, stslot = tid & 7;
  const int scol = 8 * (stslot ^ (strow & 7));
  const bf16_t* bA = &A [(m0 + strow) * K + scol];
  const bf16_t* bB = &Bt[(n0 + strow) * K + scol];

  f32x4 acc[MBQ * 2][4] = {};
  bf16x8 fa[2][MBQ][2], fb[2][2][2];
  const int NKT = K / 64;

  auto stA = [&](int bb, int h, int tt) {
    gload_lds16(bA + (long)(h * 128) * K + (long)tt * 64,
                &AsF[(bb * 2 + h) * 8192 + wid * 512]);
    gload_lds16(bA + (long)(h * 128 + 64) * K + (long)tt * 64,
                &AsF[(bb * 2 + h) * 8192 + 4096 + wid * 512]);
  };
  auto stBh = [&](int bb, int h, int tt) {      // TN==256: one 128-row half
    gload_lds16(bB + (long)(h * 128) * K + (long)tt * 64,
                &BsF[(bb * 2 + h) * 8192 + wid * 512]);
    gload_lds16(bB + (long)(h * 128 + 64) * K + (long)tt * 64,
                &BsF[(bb * 2 + h) * 8192 + 4096 + wid * 512]);
  };
  auto stB128 = [&](int bb, int tt) {           // TN==128: both 64-row halves
    gload_lds16(bB + (long)tt * 64, &BsF[(bb * 2 + 0) * 4096 + wid * 512]);
    gload_lds16(bB + (long)64 * K + (long)tt * 64,
                &BsF[(bb * 2 + 1) * 4096 + wid * 512]);
  };
  auto rdA = [&](int bb, int mh) {
#pragma unroll
    for (int m2 = 0; m2 < MBQ; ++m2)
#pragma unroll
      for (int ks = 0; ks < 2; ++ks) {
        int r_, hf;
        if constexpr (TN == 256) { r_ = mh * 64 + m2 * 16 + lr; hf = wr; }
        else { r_ = (wr & 1) * 64 + mh * 32 + m2 * 16 + lr; hf = wr >> 1; }
        fa[mh][m2][ks] = *(const bf16x8*)&AsF[
            (bb * 2 + hf) * 8192 + r_ * 64 + (((ks << 2) | lk) ^ (r_ & 7)) * 8];
      }
  };
  auto rdB = [&](int bb, int nh) {
#pragma unroll
    for (int n2 = 0; n2 < 2; ++n2)
#pragma unroll
      for (int ks = 0; ks < 2; ++ks) {
        if constexpr (TN == 256) {
          const int rw_ = wc * 64 + nh * 32 + n2 * 16 + lr;
          fb[nh][n2][ks] = *(const bf16x8*)&BsF[
              (bb * 2 + (wc >> 1)) * 8192 + (rw_ & 127) * 64 +
              (((ks << 2) | lk) ^ (rw_ & 7)) * 8];
        } else {
          const int rB = nh * 32 + n2 * 16 + lr;
          fb[nh][n2][ks] = *(const bf16x8*)&BsF[
              (bb * 2 + wc) * 4096 + rB * 64 +
              (((ks << 2) | lk) ^ (rB & 7)) * 8];
        }
      }
  };
  auto mm = [&](int mh, int nh) {
#pragma unroll
    for (int m2 = 0; m2 < MBQ; ++m2)
#pragma unroll
      for (int n2 = 0; n2 < 2; ++n2)
#pragma unroll
        for (int ks = 0; ks < 2; ++ks)
          acc[mh * MBQ + m2][nh * 2 + n2] =
              mfma16(fa[mh][m2][ks], fb[nh][n2][ks], acc[mh * MBQ + m2][nh * 2 + n2]);
  };

  // prologue: stage all of tile 0; drain; publish.
  stA(0, 0, 0); stA(0, 1, 0);
  if constexpr (TN == 256) { stBh(0, 0, 0); stBh(0, 1, 0); }
  else                     { stB128(0, 0); }
  GP_VM0; GP_BAR;

  for (int t = 0; t < NKT; ++t) {
    const int b = t & 1, nbuf = b ^ 1;
    // ph0: reads fa[0]+fb[0] (pre-barrier), stage A(t+1)
    rdA(b, 0); rdB(b, 0);
    if (t + 1 < NKT) {
      if constexpr (TN == 256) { stA(nbuf, 0, t + 1); stA(nbuf, 1, t + 1); }
      else                     { stA(nbuf, 0, t + 1); }
    }
    GP_BAR; GP_LG0; GP_SCB; GP_P1; mm(0, 0); GP_P0; GP_BAR;
    // ph1: reads fb[1], stage B(t+1) [256] / A-h1(t+1) [128]
    rdB(b, 1);
    if (t + 1 < NKT) {
      if constexpr (TN == 256) { stBh(nbuf, 0, t + 1); stBh(nbuf, 1, t + 1); }
      else                     { stA(nbuf, 1, t + 1); }
    }
    GP_BAR; GP_LG0; GP_SCB; GP_P1; mm(0, 1); GP_P0; GP_BAR;
    // ph2: reads fa[1], stage B(t+1) [128]
    rdA(b, 1);
    if (t + 1 < NKT) { if constexpr (TN == 128) stB128(nbuf, t + 1); }
    GP_BAR; GP_LG0; GP_SCB; GP_P1; mm(1, 0); GP_P0; GP_BAR;
    // ph3: drain t+1's stage loads (1-3 phases old), publish
    GP_VM0; GP_BAR;
    GP_P1; mm(1, 1); GP_P0; GP_BAR;
  }

#pragma unroll
  for (int mb = 0; mb < MBQ * 2; ++mb)
#pragma unroll
    for (int nb = 0; nb < 4; ++nb)
#pragma unroll
      for (int i = 0; i < 4; ++i) {
        long r;
        if constexpr (TN == 256)
          r = m0 + wr * 128 + (mb >> 2) * 64 + (mb & 3) * 16 + lk * 4 + i;
        else
          r = m0 + wr * 64 + (mb >> 1) * 32 + (mb & 1) * 16 + lk * 4 + i;
        const long cc = n0 + wc * 64 + (nb >> 1) * 32 + (nb & 1) * 16 + lr;
        float v = acc[mb][nb][i];
        if constexpr (MODE == 0) {
          if (cc < 1024) v *= QSCALE;
          ((bf16_t*)C)[r * N + cc] = (bf16_t)v;
        } else if constexpr (MODE == 1) {
          ((bf16_t*)C)[r * N + cc] = (bf16_t)(0.5f * v + (float)aux2[r * N + cc]);
        } else if constexpr (MODE == 2) {
          ((bf16_t*)C)[r * N + cc] = (bf16_t)fmaxf(v + aux1[cc], 0.0f);
        } else {
          ((bf16_t*)C)[r * N + cc] = (bf16_t)(v + aux1[cc] + (float)aux2[r * N + cc]);
        }
      }
}

// ---------------------------------------------------------------------------
// flash attention v11 (round 15, unchanged — ~90 µs): kf + all tr-reads up
// front, QKT, both softmaxes, single drain + merged 32-MFMA PV.
// ---------------------------------------------------------------------------
__global__ void __launch_bounds__(256, 2) attn_kernel(
    const bf16_t* __restrict__ QKV, bf16_t* __restrict__ Ctx)
{
  __shared__ bf16_t Ks[2][64 * 64];
  __shared__ bf16_t Vt[2][64 * 64];
  const int tid = threadIdx.x;
  const int lane = tid & 63, w = tid >> 6;
  const int lr = lane & 15, lk = lane >> 4;
  const int bh = blockIdx.x, b = bh >> 4, h = bh & 15;
  const long rowbase = (long)b * SS;
  const int q0 = blockIdx.y * 128;
  const int qcol = h * 64, kcol = EE + h * 64, vcol = 2 * EE + h * 64;
  constexpr int NT = SS / 64;

  bf16x8 qf[2][2];
#pragma unroll
  for (int mb = 0; mb < 2; ++mb)
#pragma unroll
    for (int ks = 0; ks < 2; ++ks)
      qf[mb][ks] = *(const bf16x8*)&QKV[
          (rowbase + q0 + w * 32 + mb * 16 + lr) * 3072 + qcol + ks * 32 + lk * 8];

  const int ksl = ((lane & 7) ^ ((lane >> 3) & 7)) * 8;
  const bf16_t* sK0 = &QKV[(rowbase + (2 * w + 0) * 8 + (lane >> 3)) * 3072 + kcol + ksl];
  const bf16_t* sK1 = &QKV[(rowbase + (2 * w + 1) * 8 + (lane >> 3)) * 3072 + kcol + ksl];
  const int vk = 4 * (lane >> 3) + ((lane >> 1) & 3);
  const int vd = 16 * w + 8 * (lane & 1);
  const bf16_t* sV0 = &QKV[(rowbase + vk) * 3072 + vcol + vd];
  const bf16_t* sV1 = &QKV[(rowbase + 32 + vk) * 3072 + vcol + vd];

  auto stage = [&](int t) {
    const int buf = t & 1;
    const long off = (long)t * 64 * 3072;
    gload_lds16(sK0 + off, &Ks[buf][(2 * w + 0) * 512]);
    gload_lds16(sK1 + off, &Ks[buf][(2 * w + 1) * 512]);
    gload_lds16(sV0 + off, &Vt[buf][(2 * w + 0) * 512]);
    gload_lds16(sV1 + off, &Vt[buf][(2 * w + 1) * 512]);
  };

  const unsigned vtr_base =
      (unsigned)(uintptr_t)(__attribute__((address_space(3))) void*)&Vt[0][0]
      + 2u * (unsigned)(lr + lk * 64);

  f32x4 oacc[2][4] = {};
  float lsum[2] = {0.0f, 0.0f};

  stage(0);

  for (int t = 0; t < NT; ++t) {
    const int buf = t & 1;
    __syncthreads();
    if (t + 1 < NT) stage(t + 1);

    bf16x8 kf[4][2];
#pragma unroll
    for (int nb = 0; nb < 4; ++nb)
#pragma unroll
      for (int ks = 0; ks < 2; ++ks)
        kf[nb][ks] = *(const bf16x8*)&Ks[buf][
            (nb * 16 + lr) * 64 + ((ks * 4 + lk) ^ (lr & 7)) * 8];
    __builtin_amdgcn_sched_barrier(0);

    const unsigned va = vtr_base + (unsigned)buf * 8192u;
    bf16x4v vlo[4][2], vhi[4][2];
    vlo[0][0] = tr8<   0>(va);  vhi[0][0] = tr8< 512>(va);
    vlo[0][1] = tr8<1024>(va);  vhi[0][1] = tr8<1536>(va);
    vlo[1][0] = tr8<2048>(va);  vhi[1][0] = tr8<2560>(va);
    vlo[1][1] = tr8<3072>(va);  vhi[1][1] = tr8<3584>(va);
    vlo[2][0] = tr8<4096>(va);  vhi[2][0] = tr8<4608>(va);
    vlo[2][1] = tr8<5120>(va);  vhi[2][1] = tr8<5632>(va);
    vlo[3][0] = tr8<6144>(va);  vhi[3][0] = tr8<6656>(va);
    vlo[3][1] = tr8<7168>(va);  vhi[3][1] = tr8<7680>(va);

    asm volatile("s_waitcnt lgkmcnt(15)" ::: "memory");
    __builtin_amdgcn_sched_barrier(0);

    f32x4 sacc[2][4] = {};
    __builtin_amdgcn_s_setprio(1);
#pragma unroll
    for (int mb = 0; mb < 2; ++mb)
#pragma unroll
      for (int nb = 0; nb < 4; ++nb)
#pragma unroll
        for (int ks = 0; ks < 2; ++ks)
          sacc[mb][nb] = mfma16(kf[nb][ks], qf[mb][ks], sacc[mb][nb]);
    __builtin_amdgcn_s_setprio(0);

    bf16x8 pfm[2][2];
#pragma unroll
    for (int mb = 0; mb < 2; ++mb) {
      float psum = 0.0f;
      u32x4 pk[2];
#pragma unroll
      for (int nb = 0; nb < 4; ++nb)
#pragma unroll
        for (int p = 0; p < 2; ++p) {
          const float a = __builtin_amdgcn_exp2f(sacc[mb][nb][2 * p]);
          const float bb = __builtin_amdgcn_exp2f(sacc[mb][nb][2 * p + 1]);
          psum += a + bb;
          unsigned pr;
          asm("v_cvt_pk_bf16_f32 %0, %1, %2" : "=v"(pr) : "v"(a), "v"(bb));
          pk[nb >> 1][(nb & 1) * 2 + p] = pr;
        }
      lsum[mb] += psum;
      pfm[mb][0] = __builtin_bit_cast(bf16x8, pk[0]);
      pfm[mb][1] = __builtin_bit_cast(bf16x8, pk[1]);
    }

    asm volatile("s_waitcnt lgkmcnt(0)" ::: "memory");
    __builtin_amdgcn_sched_barrier(0);
    bf16x8 vf[4][2];
#pragma unroll
    for (int nb = 0; nb < 4; ++nb)
#pragma unroll
      for (int ks = 0; ks < 2; ++ks)
        vf[nb][ks] = __builtin_shufflevector(
            vlo[nb][ks], vhi[nb][ks], 0, 1, 2, 3, 4, 5, 6, 7);
    __builtin_amdgcn_s_setprio(1);
#pragma unroll
    for (int mb = 0; mb < 2; ++mb)
#pragma unroll
      for (int nb = 0; nb < 4; ++nb)
#pragma unroll
        for (int ks = 0; ks < 2; ++ks)
          oacc[mb][nb] = mfma16(pfm[mb][ks], vf[nb][ks], oacc[mb][nb]);
    __builtin_amdgcn_s_setprio(0);
  }

#pragma unroll
  for (int mb = 0; mb < 2; ++mb) {
    float l = lsum[mb];
    l += __shfl_xor(l, 16);
    l += __shfl_xor(l, 32);
    float li[4];
#pragma unroll
    for (int i = 0; i < 4; ++i) li[i] = 1.0f / __shfl(l, lk * 4 + i);
#pragma unroll
    for (int nb = 0; nb < 4; ++nb)
#pragma unroll
      for (int i = 0; i < 4; ++i) {
        const long r = rowbase + q0 + w * 32 + mb * 16 + lk * 4 + i;
        Ctx[r * 2048 + h * 64 + nb * 16 + lr] = (bf16_t)(oacc[mb][nb][i] * li[i]);
      }
  }
}

// ---------------------------------------------------------------------------
// LayerNorm over rows of 1024, bf16 input; one block (256 thr) per row.
// ---------------------------------------------------------------------------
__device__ __forceinline__ void ln_reduce4(const float4& v, int tid,
                                           float& mu, float& rs) {
  float s = v.x + v.y + v.z + v.w;
  float ss = v.x * v.x + v.y * v.y + v.z * v.z + v.w * v.w;
#pragma unroll
  for (int off = 1; off < 64; off <<= 1) {
    s += __shfl_xor(s, off);
    ss += __shfl_xor(ss, off);
  }
  __shared__ float wsum[4], wsq[4];
  if ((tid & 63) == 0) { wsum[tid >> 6] = s; wsq[tid >> 6] = ss; }
  __syncthreads();
  s = wsum[0] + wsum[1] + wsum[2] + wsum[3];
  ss = wsq[0] + wsq[1] + wsq[2] + wsq[3];
  mu = s * (1.0f / EE);
  rs = rsqrtf(ss * (1.0f / EE) - mu * mu + 1e-5f);
}

__global__ void __launch_bounds__(256) ln_bf16_kernel(
    const bf16_t* __restrict__ pre, const float* __restrict__ g,
    const float* __restrict__ bt, bf16_t* __restrict__ out)
{
  const int r = blockIdx.x, tid = threadIdx.x;
  const long base = (long)r * EE + tid * 4;
  const bf16x4v pv = *(const bf16x4v*)&pre[base];
  float4 v = make_float4((float)pv[0], (float)pv[1], (float)pv[2], (float)pv[3]);
  float mu, rs;
  ln_reduce4(v, tid, mu, rs);
  const float4 gv = *(const float4*)&g[tid * 4];
  const float4 bv = *(const float4*)&bt[tid * 4];
  bf16x4v o;
  o[0] = (bf16_t)((v.x - mu) * rs * gv.x + bv.x);
  o[1] = (bf16_t)((v.y - mu) * rs * gv.y + bv.y);
  o[2] = (bf16_t)((v.z - mu) * rs * gv.z + bv.z);
  o[3] = (bf16_t)((v.w - mu) * rs * gv.w + bv.w);
  *(bf16x4v*)&out[base] = o;
}

__global__ void __launch_bounds__(256) ln_f32_kernel(
    const bf16_t* __restrict__ pre, const float* __restrict__ g,
    const float* __restrict__ bt, float* __restrict__ out)
{
  const int r = blockIdx.x, tid = threadIdx.x;
  const long base = (long)r * EE + tid * 4;
  const bf16x4v pv = *(const bf16x4v*)&pre[base];
  float4 v = make_float4((float)pv[0], (float)pv[1], (float)pv[2], (float)pv[3]);
  float mu, rs;
  ln_reduce4(v, tid, mu, rs);
  const float4 gv = *(const float4*)&g[tid * 4];
  const float4 bv = *(const float4*)&bt[tid * 4];
  float4 o;
  o.x = (v.x - mu) * rs * gv.x + bv.x;
  o.y = (v.y - mu) * rs * gv.y + bv.y;
  o.z = (v.z - mu) * rs * gv.z + bv.z;
  o.w = (v.w - mu) * rs * gv.w + bv.w;
  *(float4*)&out[base] = o;
}

// ---------------------------------------------------------------------------
extern "C" void kernel_launch(void* const* d_in, const int* in_sizes, int n_in,
                              void* d_out, int out_size, void* d_ws, size_t ws_size,
                              hipStream_t stream)
{
  (void)in_sizes; (void)n_in; (void)out_size; (void)ws_size;
  const float* x     = (const float*)d_in[0];
  const float* Wq    = (const float*)d_in[1];
  const float* Wk    = (const float*)d_in[2];
  const float* Wv    = (const float*)d_in[3];
  const float* Wo    = (const float*)d_in[4];
  const float* theta = (const float*)d_in[5];
  const float* Wcq   = (const float*)d_in[6];
  const float* ln1g  = (const float*)d_in[7];
  const float* ln1b  = (const float*)d_in[8];
  const float* W1    = (const float*)d_in[9];
  const float* b1    = (const float*)d_in[10];
  const float* W2    = (const float*)d_in[11];
  const float* b2    = (const float*)d_in[12];
  const float* ln2g  = (const float*)d_in[13];
  const float* ln2b  = (const float*)d_in[14];

  // workspace layout (lifetime-aliased)
  char* ws = (char*)d_ws;
  const size_t MB = 1ull << 20;
  bf16_t* xbf     = (bf16_t*)(ws + 0);          // 16MB: bf16(x), later x1
  bf16_t* QKV     = (bf16_t*)(ws + 16 * MB);    // 48MB: q|k|v
  bf16_t* preLN1  = (bf16_t*)(ws + 16 * MB);    // 16MB alias (QKV dead after attn)
  bf16_t* A2      = (bf16_t*)(ws + 64 * MB);    // 32MB: [ctx | qh]
  bf16_t* preLN2  = (bf16_t*)(ws + 64 * MB);    // alias (A2 dead after attn-out)
  bf16_t* H1      = (bf16_t*)(ws + 96 * MB);    // 64MB: FFN hidden
  bf16_t* BtQKV   = (bf16_t*)(ws + 160 * MB);   // 6MB
  bf16_t* Bt2     = (bf16_t*)(ws + 166 * MB);   // 4MB
  bf16_t* BtW1    = (bf16_t*)(ws + 170 * MB);   // 8MB
  bf16_t* BtW2    = (bf16_t*)(ws + 178 * MB);   // 8MB

  prep_x_kernel<<<4096, 256, 0, stream>>>(x, theta, xbf, A2);
  transpose_all_kernel<<<13312, dim3(32, 8), 0, stream>>>(
      Wq, Wk, Wv, Wo, Wcq, W1, W2, BtQKV, Bt2, BtW1, BtW2);

  // 1) QKV projection — 8-phase 256x128 (768 blocks = 3.0 exact rounds)
  gemm8p<0, 128><<<dim3(24, 32), 512, 0, stream>>>(xbf, BtQKV, QKV, 8192, 3072, 1024, nullptr, nullptr);
  // 2) flash attention -> ctx (left half of A2)
  attn_kernel<<<dim3(64, 16), 256, 0, stream>>>(QKV, A2);
  // 3) fused attn-out: bf16( 0.5*([ctx|qh] @ [Wo;Wcq]) + x ) — 8p 256x128
  gemm8p<1, 128><<<dim3(8, 32), 512, 0, stream>>>(A2, Bt2, preLN1, 8192, 1024, 2048, nullptr, xbf);
  // 4) LN1 -> x1 (bf16, overwrites xbf)
  ln_bf16_kernel<<<8192, 256, 0, stream>>>(preLN1, ln1g, ln1b, xbf);
  // 5) FFN1: relu(x1@W1 + b1) -> H1 — 8-phase 256x256 (512 blocks)
  gemm8p<2, 256><<<dim3(16, 32), 512, 0, stream>>>(xbf, BtW1, H1, 8192, 4096, 1024, b1, nullptr);
  // 6) FFN2: bf16( H1@W2 + b2 + x1 ) — 8p 256x128 (256 blocks = 1.0 round)
  gemm8p<3, 128><<<dim3(8, 32), 512, 0, stream>>>(H1, BtW2, preLN2, 8192, 1024, 4096, b2, xbf);
  // 7) LN2 -> output (f32)
  ln_f32_kernel<<<8192, 256, 0, stream>>>(preLN2, ln2g, ln2b, (float*)d_out);
}

// Round 18
// 399.019 us; speedup vs baseline: 1.0675x; 1.0675x over previous
//
#include <hip/hip_runtime.h>
#include <hip/hip_bf16.h>

typedef __bf16 bf16_t;
typedef bf16_t bf16x8 __attribute__((ext_vector_type(8)));
typedef bf16_t bf16x4v __attribute__((ext_vector_type(4)));
typedef float f32x4 __attribute__((ext_vector_type(4)));
typedef unsigned u32x4 __attribute__((ext_vector_type(4)));

// problem constants
static constexpr int EE = 1024;   // E
static constexpr int SS = 2048;   // S
static constexpr int DK = 64;
static constexpr float QSCALE = 0.125f * 1.44269504f;

__device__ __forceinline__ void gload_lds16(const void* g, void* l) {
  __builtin_amdgcn_global_load_lds(
      (__attribute__((address_space(1))) void*)g,
      (__attribute__((address_space(3))) void*)l, 16, 0, 0);
}

__device__ __forceinline__ f32x4 mfma16(bf16x8 a, bf16x8 b, f32x4 c) {
  return __builtin_amdgcn_mfma_f32_16x16x32_bf16(a, b, c, 0, 0, 0);
}

template<int OFF>
__device__ __forceinline__ bf16x4v tr8(unsigned va) {
  bf16x4v d;
  asm volatile("ds_read_b64_tr_b16 %0, %1 offset:%c2"
               : "=v"(d) : "v"(va), "i"(OFF));
  return d;
}

// ---------------------------------------------------------------------------
// prep: x -> bf16, and qh = cos(x + theta) into A2 right half.
// ---------------------------------------------------------------------------
__global__ void __launch_bounds__(256) prep_x_kernel(
    const float* __restrict__ x, const float* __restrict__ theta,
    bf16_t* __restrict__ xbf, bf16_t* __restrict__ A2)
{
  const long t = (long)blockIdx.x * 256 + threadIdx.x;
  const long e0 = t * 8;
  const int col = (int)(e0 & (EE - 1));
  const long row = e0 >> 10;
  const float4 v0 = *(const float4*)&x[e0];
  const float4 v1 = *(const float4*)&x[e0 + 4];
  float xs[8] = {v0.x, v0.y, v0.z, v0.w, v1.x, v1.y, v1.z, v1.w};
  const int d0 = col & (DK - 1);
  bf16x8 xb, qb;
#pragma unroll
  for (int j = 0; j < 8; ++j) {
    xb[j] = (bf16_t)xs[j];
    qb[j] = (bf16_t)__cosf(xs[j] + theta[d0 + j]);
  }
  *(bf16x8*)&xbf[e0] = xb;
  *(bf16x8*)&A2[row * 2048 + EE + col] = qb;
}

// ---------------------------------------------------------------------------
// fused weight transpose + f32->bf16 for ALL seven weights in ONE launch.
// ---------------------------------------------------------------------------
__global__ void __launch_bounds__(256) transpose_all_kernel(
    const float* __restrict__ Wq, const float* __restrict__ Wk,
    const float* __restrict__ Wv, const float* __restrict__ Wo,
    const float* __restrict__ Wcq, const float* __restrict__ W1,
    const float* __restrict__ W2,
    bf16_t* __restrict__ BtQKV, bf16_t* __restrict__ Bt2,
    bf16_t* __restrict__ BtW1, bf16_t* __restrict__ BtW2)
{
  const int bid = blockIdx.x;
  const float* src; bf16_t* dst; int N; long dstride, dcol0; int bx, by;
  if (bid < 5120) {
    const int seg = bid >> 10, r = bid & 1023;
    bx = r & 31; by = r >> 5; N = 1024;
    if      (seg == 0) { src = Wq;  dst = BtQKV;               dstride = 1024; dcol0 = 0; }
    else if (seg == 1) { src = Wk;  dst = BtQKV + 1024 * 1024; dstride = 1024; dcol0 = 0; }
    else if (seg == 2) { src = Wv;  dst = BtQKV + 2048 * 1024; dstride = 1024; dcol0 = 0; }
    else if (seg == 3) { src = Wo;  dst = Bt2;                 dstride = 2048; dcol0 = 0; }
    else               { src = Wcq; dst = Bt2;                 dstride = 2048; dcol0 = 1024; }
  } else if (bid < 9216) {
    const int r = bid - 5120;
    src = W1; dst = BtW1; N = 4096; dstride = 1024; dcol0 = 0;
    bx = r & 127; by = r >> 7;
  } else {
    const int r = bid - 9216;
    src = W2; dst = BtW2; N = 1024; dstride = 4096; dcol0 = 0;
    bx = r & 31; by = r >> 5;
  }
  __shared__ float tile[32][33];
  const int tx = threadIdx.x, ty = threadIdx.y;
  const long n0 = (long)bx * 32, k0 = (long)by * 32;
#pragma unroll
  for (int j = 0; j < 4; ++j)
    tile[ty + j * 8][tx] = src[(k0 + ty + j * 8) * N + n0 + tx];
  __syncthreads();
#pragma unroll
  for (int j = 0; j < 4; ++j)
    dst[(n0 + ty + j * 8) * dstride + dcol0 + k0 + tx] = (bf16_t)tile[tx][ty + j * 8];
}

// ---------------------------------------------------------------------------
// gemm8p v2 — m201-faithful 8-phase 256x256 GEMM, BK=64, 512 thr = 8 waves
// (2Mx4N), per-wave 128x64, acc[8][4]. LDS 128KB: [2 buf][2 half][128][64]
// per operand. Quadrant ds_reads issued in the PRE-barrier region (template
// order reads->stage->BAR->lgkm0->MFMA->BAR) so their latency is absorbed by
// the barrier wait / other waves' MFMA. Stage: t+1's A halves in ph0, B
// halves in ph1; single vmcnt(0) in ph3. Publish/WAR ledger verified.
// Swizzle: 16B slot ^= row&7 at pre-swizzled SOURCE and at ds_read.
// MODE 0: C bf16, cols<1024 scaled by QSCALE (QKV). MODE 2: relu+bias (FFN1).
// ---------------------------------------------------------------------------
#define GP_BAR __builtin_amdgcn_s_barrier()
#define GP_LG0 asm volatile("s_waitcnt lgkmcnt(0)" ::: "memory")
#define GP_VM0 asm volatile("s_waitcnt vmcnt(0)" ::: "memory")
#define GP_SCB __builtin_amdgcn_sched_barrier(0)
#define GP_P1 __builtin_amdgcn_s_setprio(1)
#define GP_P0 __builtin_amdgcn_s_setprio(0)
#define GP_SA(bb, h, tt) do { \
    gload_lds16(bA + (long)((h) * 128) * K + (long)(tt) * 64, \
                &AsF[((bb) * 2 + (h)) * 8192 + wid * 512]); \
    gload_lds16(bA + (long)((h) * 128 + 64) * K + (long)(tt) * 64, \
                &AsF[((bb) * 2 + (h)) * 8192 + 4096 + wid * 512]); } while (0)
#define GP_SB(bb, h, tt) do { \
    gload_lds16(bB + (long)((h) * 128) * K + (long)(tt) * 64, \
                &BsF[((bb) * 2 + (h)) * 8192 + wid * 512]); \
    gload_lds16(bB + (long)((h) * 128 + 64) * K + (long)(tt) * 64, \
                &BsF[((bb) * 2 + (h)) * 8192 + 4096 + wid * 512]); } while (0)
#define GP_RA(bb, mh) do { \
    _Pragma("unroll") for (int mb2 = 0; mb2 < 4; ++mb2) \
    _Pragma("unroll") for (int ks = 0; ks < 2; ++ks) { \
      const int r_ = (mh) * 64 + mb2 * 16 + lr; \
      fa[mh][mb2][ks] = *(const bf16x8*)&AsF[ \
          ((bb) * 2 + wr) * 8192 + r_ * 64 + (((ks << 2) | lk) ^ (r_ & 7)) * 8]; } } while (0)
#define GP_RB(bb, nh) do { \
    _Pragma("unroll") for (int nb2 = 0; nb2 < 2; ++nb2) \
    _Pragma("unroll") for (int ks = 0; ks < 2; ++ks) { \
      const int rw_ = wc * 64 + (nh) * 32 + nb2 * 16 + lr; \
      fb[nh][nb2][ks] = *(const bf16x8*)&BsF[ \
          ((bb) * 2 + (wc >> 1)) * 8192 + (rw_ & 127) * 64 + (((ks << 2) | lk) ^ (rw_ & 7)) * 8]; } } while (0)
#define GP_MM(mh, nh) do { \
    _Pragma("unroll") for (int mb2 = 0; mb2 < 4; ++mb2) \
    _Pragma("unroll") for (int nb2 = 0; nb2 < 2; ++nb2) \
    _Pragma("unroll") for (int ks = 0; ks < 2; ++ks) \
      acc[(mh) * 4 + mb2][(nh) * 2 + nb2] = \
          mfma16(fa[mh][mb2][ks], fb[nh][nb2][ks], acc[(mh) * 4 + mb2][(nh) * 2 + nb2]); } while (0)

template<int MODE>
__global__ void __launch_bounds__(512, 2) gemm8p(
    const bf16_t* __restrict__ A, const bf16_t* __restrict__ Bt,
    void* __restrict__ C, int M, int N, int K, const float* __restrict__ aux1)
{
  __shared__ bf16_t AsF[32768];
  __shared__ bf16_t BsF[32768];
  const int tid = threadIdx.x;
  const int lane = tid & 63, wid = tid >> 6;
  const int wr = wid >> 2, wc = wid & 3;
  const int lr = lane & 15, lk = lane >> 4;
  const int gx = gridDim.x;
  const int nwg = gx * gridDim.y;
  const int bid = blockIdx.y * gx + blockIdx.x;
  const int swz = (bid & 7) * (nwg >> 3) + (bid >> 3);   // nwg % 8 == 0
  const long m0 = (long)(swz / gx) * 256;
  const long n0 = (long)(swz % gx) * 256;

  // staging: thread owns 16B slot (tid&7) of row (tid>>3); source col
  // pre-swizzled slot^=(row&7); LDS dest linear.
  const int strow = tid >> 3, stslot = tid & 7;
  const int scol = 8 * (stslot ^ (strow & 7));
  const bf16_t* bA = &A [(m0 + strow) * K + scol];
  const bf16_t* bB = &Bt[(n0 + strow) * K + scol];

  f32x4 acc[8][4] = {};
  bf16x8 fa[2][4][2], fb[2][2][2];
  const int NKT = K / 64;

  // prologue: stage all 4 halves of tile 0; drain; publish.
  GP_SA(0, 0, 0); GP_SA(0, 1, 0);
  GP_SB(0, 0, 0); GP_SB(0, 1, 0);
  GP_VM0; GP_BAR;

  for (int t = 0; t < NKT; ++t) {
    const int b = t & 1, nb = b ^ 1;
    // ph0: reads fa[0]+fb[0] (pre-barrier), stage A halves of t+1
    GP_RA(b, 0); GP_RB(b, 0);
    if (t + 1 < NKT) { GP_SA(nb, 0, t + 1); GP_SA(nb, 1, t + 1); }
    GP_BAR; GP_LG0; GP_SCB; GP_P1; GP_MM(0, 0); GP_P0; GP_BAR;
    // ph1: reads fb[1], stage B halves of t+1
    GP_RB(b, 1);
    if (t + 1 < NKT) { GP_SB(nb, 0, t + 1); GP_SB(nb, 1, t + 1); }
    GP_BAR; GP_LG0; GP_SCB; GP_P1; GP_MM(0, 1); GP_P0; GP_BAR;
    // ph2: reads fa[1]
    GP_RA(b, 1);
    GP_BAR; GP_LG0; GP_SCB; GP_P1; GP_MM(1, 0); GP_P0; GP_BAR;
    // ph3: no reads; drain t+1's stage loads (issued ph0/ph1, ~2 phases old)
    GP_VM0; GP_BAR;
    GP_P1; GP_MM(1, 1); GP_P0; GP_BAR;
  }

#pragma unroll
  for (int mb = 0; mb < 8; ++mb)
#pragma unroll
    for (int nb = 0; nb < 4; ++nb)
#pragma unroll
      for (int i = 0; i < 4; ++i) {
        const long r = m0 + wr * 128 + (mb >> 2) * 64 + (mb & 3) * 16 + lk * 4 + i;
        const long cc = n0 + wc * 64 + (nb >> 1) * 32 + (nb & 1) * 16 + lr;
        float v = acc[mb][nb][i];
        if constexpr (MODE == 0) {
          if (cc < 1024) v *= QSCALE;
          ((bf16_t*)C)[r * N + cc] = (bf16_t)v;
        } else {
          ((bf16_t*)C)[r * N + cc] = (bf16_t)fmaxf(v + aux1[cc], 0.0f);
        }
      }
}

// ---------------------------------------------------------------------------
// 256x128 deep-pipelined GEMM, depth-3 LDS ring (round-14 structure, kept
// for the N=1024 outputs). MODE 1 attn-out / 3 FFN2.
// ---------------------------------------------------------------------------
template<int MODE>
__global__ void __launch_bounds__(512, 4) gemm128(
    const bf16_t* __restrict__ A, const bf16_t* __restrict__ Bt,
    void* __restrict__ C, int M, int N, int K,
    const float* __restrict__ aux1, const bf16_t* __restrict__ aux2)
{
  __shared__ bf16_t As[3][256 * 32];
  __shared__ bf16_t Bs[3][128 * 32];
  const int tid = threadIdx.x;
  const int lane = tid & 63, wid = tid >> 6;
  const int wr = wid >> 1, wc = wid & 1;
  const int lr = lane & 15, lk = lane >> 4;
  const int gx = gridDim.x;
  const int nwg = gx * gridDim.y;
  const int bid = blockIdx.y * gx + blockIdx.x;
  const int swz = (bid & 7) * (nwg >> 3) + (bid >> 3);   // nwg % 8 == 0
  const long m0 = (long)(swz / gx) * 256;
  const long n0 = (long)(swz % gx) * 128;

  const int rql = lane >> 2;
  const int sl  = lane & 3;
  const int rA0 = wid * 32 + rql, rA1 = wid * 32 + 16 + rql;
  const bf16_t* sA0 = &A [(m0 + rA0) * K + 8 * (sl ^ ((rA0 >> 1) & 3))];
  const bf16_t* sA1 = &A [(m0 + rA1) * K + 8 * (sl ^ ((rA1 >> 1) & 3))];
  const int rB0 = wid * 16 + rql;
  const bf16_t* sB0 = &Bt[(n0 + rB0) * K + 8 * (sl ^ ((rB0 >> 1) & 3))];
  const int loA = wid * 1024;
  const int loB = wid * 512;

  f32x4 acc[4][4] = {};
  const int NKT = K / 32;

  auto stage = [&](int t) {
    const int s = t % 3;
    gload_lds16(sA0 + (long)t * 32, &As[s][loA]);
    gload_lds16(sA1 + (long)t * 32, &As[s][loA + 512]);
    gload_lds16(sB0 + (long)t * 32, &Bs[s][loB]);
  };

  stage(0); stage(1);
  asm volatile("s_waitcnt vmcnt(3)" ::: "memory");
  __builtin_amdgcn_s_barrier();

  for (int t = 0; t < NKT; ++t) {
    const int s = t % 3;
    bf16x8 bfr[4], af1[2], af2[2];
#pragma unroll
    for (int nb = 0; nb < 4; ++nb) {
      const int rw = wc * 64 + nb * 16 + lr;
      bfr[nb] = *(const bf16x8*)&Bs[s][rw * 32 + (lk ^ ((rw >> 1) & 3)) * 8];
    }
#pragma unroll
    for (int mb = 0; mb < 2; ++mb) {
      const int rw = wr * 64 + mb * 16 + lr;
      af1[mb] = *(const bf16x8*)&As[s][rw * 32 + (lk ^ ((rw >> 1) & 3)) * 8];
    }
    __builtin_amdgcn_sched_barrier(0);
#pragma unroll
    for (int mb = 0; mb < 2; ++mb) {
      const int rw = wr * 64 + 32 + mb * 16 + lr;
      af2[mb] = *(const bf16x8*)&As[s][rw * 32 + (lk ^ ((rw >> 1) & 3)) * 8];
    }
    if (t + 2 < NKT) stage(t + 2);
    asm volatile("s_waitcnt lgkmcnt(2)" ::: "memory");
    __builtin_amdgcn_sched_barrier(0);
    __builtin_amdgcn_s_setprio(1);
#pragma unroll
    for (int mb = 0; mb < 2; ++mb)
#pragma unroll
      for (int nb = 0; nb < 4; ++nb)
        acc[mb][nb] = mfma16(af1[mb], bfr[nb], acc[mb][nb]);
    __builtin_amdgcn_s_setprio(0);
    asm volatile("s_waitcnt lgkmcnt(0)" ::: "memory");
    __builtin_amdgcn_sched_barrier(0);
    __builtin_amdgcn_s_setprio(1);
#pragma unroll
    for (int mb = 0; mb < 2; ++mb)
#pragma unroll
      for (int nb = 0; nb < 4; ++nb)
        acc[2 + mb][nb] = mfma16(af2[mb], bfr[nb], acc[2 + mb][nb]);
    __builtin_amdgcn_s_setprio(0);
    if (t + 2 < NKT)      { asm volatile("s_waitcnt vmcnt(3)" ::: "memory"); }
    else if (t + 1 < NKT) { asm volatile("s_waitcnt vmcnt(0)" ::: "memory"); }
    __builtin_amdgcn_s_barrier();
  }

#pragma unroll
  for (int mb = 0; mb < 4; ++mb)
#pragma unroll
    for (int nb = 0; nb < 4; ++nb)
#pragma unroll
      for (int i = 0; i < 4; ++i) {
        const long r = m0 + wr * 64 + mb * 16 + lk * 4 + i;
        const long cc = n0 + wc * 64 + nb * 16 + lr;
        float v = acc[mb][nb][i];
        if constexpr (MODE == 1) {
          ((bf16_t*)C)[r * N + cc] = (bf16_t)(0.5f * v + (float)aux2[r * N + cc]);
        } else {
          ((bf16_t*)C)[r * N + cc] = (bf16_t)(v + aux1[cc] + (float)aux2[r * N + cc]);
        }
      }
}

// ---------------------------------------------------------------------------
// flash attention v11 (round 15, unchanged — ~90 µs): kf + all tr-reads up
// front, QKT, both softmaxes, single drain + merged 32-MFMA PV.
// ---------------------------------------------------------------------------
__global__ void __launch_bounds__(256, 2) attn_kernel(
    const bf16_t* __restrict__ QKV, bf16_t* __restrict__ Ctx)
{
  __shared__ bf16_t Ks[2][64 * 64];
  __shared__ bf16_t Vt[2][64 * 64];
  const int tid = threadIdx.x;
  const int lane = tid & 63, w = tid >> 6;
  const int lr = lane & 15, lk = lane >> 4;
  const int bh = blockIdx.x, b = bh >> 4, h = bh & 15;
  const long rowbase = (long)b * SS;
  const int q0 = blockIdx.y * 128;
  const int qcol = h * 64, kcol = EE + h * 64, vcol = 2 * EE + h * 64;
  constexpr int NT = SS / 64;

  bf16x8 qf[2][2];
#pragma unroll
  for (int mb = 0; mb < 2; ++mb)
#pragma unroll
    for (int ks = 0; ks < 2; ++ks)
      qf[mb][ks] = *(const bf16x8*)&QKV[
          (rowbase + q0 + w * 32 + mb * 16 + lr) * 3072 + qcol + ks * 32 + lk * 8];

  const int ksl = ((lane & 7) ^ ((lane >> 3) & 7)) * 8;
  const bf16_t* sK0 = &QKV[(rowbase + (2 * w + 0) * 8 + (lane >> 3)) * 3072 + kcol + ksl];
  const bf16_t* sK1 = &QKV[(rowbase + (2 * w + 1) * 8 + (lane >> 3)) * 3072 + kcol + ksl];
  const int vk = 4 * (lane >> 3) + ((lane >> 1) & 3);
  const int vd = 16 * w + 8 * (lane & 1);
  const bf16_t* sV0 = &QKV[(rowbase + vk) * 3072 + vcol + vd];
  const bf16_t* sV1 = &QKV[(rowbase + 32 + vk) * 3072 + vcol + vd];

  auto stage = [&](int t) {
    const int buf = t & 1;
    const long off = (long)t * 64 * 3072;
    gload_lds16(sK0 + off, &Ks[buf][(2 * w + 0) * 512]);
    gload_lds16(sK1 + off, &Ks[buf][(2 * w + 1) * 512]);
    gload_lds16(sV0 + off, &Vt[buf][(2 * w + 0) * 512]);
    gload_lds16(sV1 + off, &Vt[buf][(2 * w + 1) * 512]);
  };

  const unsigned vtr_base =
      (unsigned)(uintptr_t)(__attribute__((address_space(3))) void*)&Vt[0][0]
      + 2u * (unsigned)(lr + lk * 64);

  f32x4 oacc[2][4] = {};
  float lsum[2] = {0.0f, 0.0f};

  stage(0);

  for (int t = 0; t < NT; ++t) {
    const int buf = t & 1;
    __syncthreads();
    if (t + 1 < NT) stage(t + 1);

    bf16x8 kf[4][2];
#pragma unroll
    for (int nb = 0; nb < 4; ++nb)
#pragma unroll
      for (int ks = 0; ks < 2; ++ks)
        kf[nb][ks] = *(const bf16x8*)&Ks[buf][
            (nb * 16 + lr) * 64 + ((ks * 4 + lk) ^ (lr & 7)) * 8];
    __builtin_amdgcn_sched_barrier(0);

    const unsigned va = vtr_base + (unsigned)buf * 8192u;
    bf16x4v vlo[4][2], vhi[4][2];
    vlo[0][0] = tr8<   0>(va);  vhi[0][0] = tr8< 512>(va);
    vlo[0][1] = tr8<1024>(va);  vhi[0][1] = tr8<1536>(va);
    vlo[1][0] = tr8<2048>(va);  vhi[1][0] = tr8<2560>(va);
    vlo[1][1] = tr8<3072>(va);  vhi[1][1] = tr8<3584>(va);
    vlo[2][0] = tr8<4096>(va);  vhi[2][0] = tr8<4608>(va);
    vlo[2][1] = tr8<5120>(va);  vhi[2][1] = tr8<5632>(va);
    vlo[3][0] = tr8<6144>(va);  vhi[3][0] = tr8<6656>(va);
    vlo[3][1] = tr8<7168>(va);  vhi[3][1] = tr8<7680>(va);

    asm volatile("s_waitcnt lgkmcnt(15)" ::: "memory");
    __builtin_amdgcn_sched_barrier(0);

    f32x4 sacc[2][4] = {};
    __builtin_amdgcn_s_setprio(1);
#pragma unroll
    for (int mb = 0; mb < 2; ++mb)
#pragma unroll
      for (int nb = 0; nb < 4; ++nb)
#pragma unroll
        for (int ks = 0; ks < 2; ++ks)
          sacc[mb][nb] = mfma16(kf[nb][ks], qf[mb][ks], sacc[mb][nb]);
    __builtin_amdgcn_s_setprio(0);

    bf16x8 pfm[2][2];
#pragma unroll
    for (int mb = 0; mb < 2; ++mb) {
      float psum = 0.0f;
      u32x4 pk[2];
#pragma unroll
      for (int nb = 0; nb < 4; ++nb)
#pragma unroll
        for (int p = 0; p < 2; ++p) {
          const float a = __builtin_amdgcn_exp2f(sacc[mb][nb][2 * p]);
          const float bb = __builtin_amdgcn_exp2f(sacc[mb][nb][2 * p + 1]);
          psum += a + bb;
          unsigned pr;
          asm("v_cvt_pk_bf16_f32 %0, %1, %2" : "=v"(pr) : "v"(a), "v"(bb));
          pk[nb >> 1][(nb & 1) * 2 + p] = pr;
        }
      lsum[mb] += psum;
      pfm[mb][0] = __builtin_bit_cast(bf16x8, pk[0]);
      pfm[mb][1] = __builtin_bit_cast(bf16x8, pk[1]);
    }

    asm volatile("s_waitcnt lgkmcnt(0)" ::: "memory");
    __builtin_amdgcn_sched_barrier(0);
    bf16x8 vf[4][2];
#pragma unroll
    for (int nb = 0; nb < 4; ++nb)
#pragma unroll
      for (int ks = 0; ks < 2; ++ks)
        vf[nb][ks] = __builtin_shufflevector(
            vlo[nb][ks], vhi[nb][ks], 0, 1, 2, 3, 4, 5, 6, 7);
    __builtin_amdgcn_s_setprio(1);
#pragma unroll
    for (int mb = 0; mb < 2; ++mb)
#pragma unroll
      for (int nb = 0; nb < 4; ++nb)
#pragma unroll
        for (int ks = 0; ks < 2; ++ks)
          oacc[mb][nb] = mfma16(pfm[mb][ks], vf[nb][ks], oacc[mb][nb]);
    __builtin_amdgcn_s_setprio(0);
  }

#pragma unroll
  for (int mb = 0; mb < 2; ++mb) {
    float l = lsum[mb];
    l += __shfl_xor(l, 16);
    l += __shfl_xor(l, 32);
    float li[4];
#pragma unroll
    for (int i = 0; i < 4; ++i) li[i] = 1.0f / __shfl(l, lk * 4 + i);
#pragma unroll
    for (int nb = 0; nb < 4; ++nb)
#pragma unroll
      for (int i = 0; i < 4; ++i) {
        const long r = rowbase + q0 + w * 32 + mb * 16 + lk * 4 + i;
        Ctx[r * 2048 + h * 64 + nb * 16 + lr] = (bf16_t)(oacc[mb][nb][i] * li[i]);
      }
  }
}

// ---------------------------------------------------------------------------
// LayerNorm over rows of 1024, bf16 input; one block (256 thr) per row.
// ---------------------------------------------------------------------------
__device__ __forceinline__ void ln_reduce4(const float4& v, int tid,
                                           float& mu, float& rs) {
  float s = v.x + v.y + v.z + v.w;
  float ss = v.x * v.x + v.y * v.y + v.z * v.z + v.w * v.w;
#pragma unroll
  for (int off = 1; off < 64; off <<= 1) {
    s += __shfl_xor(s, off);
    ss += __shfl_xor(ss, off);
  }
  __shared__ float wsum[4], wsq[4];
  if ((tid & 63) == 0) { wsum[tid >> 6] = s; wsq[tid >> 6] = ss; }
  __syncthreads();
  s = wsum[0] + wsum[1] + wsum[2] + wsum[3];
  ss = wsq[0] + wsq[1] + wsq[2] + wsq[3];
  mu = s * (1.0f / EE);
  rs = rsqrtf(ss * (1.0f / EE) - mu * mu + 1e-5f);
}

__global__ void __launch_bounds__(256) ln_bf16_kernel(
    const bf16_t* __restrict__ pre, const float* __restrict__ g,
    const float* __restrict__ bt, bf16_t* __restrict__ out)
{
  const int r = blockIdx.x, tid = threadIdx.x;
  const long base = (long)r * EE + tid * 4;
  const bf16x4v pv = *(const bf16x4v*)&pre[base];
  float4 v = make_float4((float)pv[0], (float)pv[1], (float)pv[2], (float)pv[3]);
  float mu, rs;
  ln_reduce4(v, tid, mu, rs);
  const float4 gv = *(const float4*)&g[tid * 4];
  const float4 bv = *(const float4*)&bt[tid * 4];
  bf16x4v o;
  o[0] = (bf16_t)((v.x - mu) * rs * gv.x + bv.x);
  o[1] = (bf16_t)((v.y - mu) * rs * gv.y + bv.y);
  o[2] = (bf16_t)((v.z - mu) * rs * gv.z + bv.z);
  o[3] = (bf16_t)((v.w - mu) * rs * gv.w + bv.w);
  *(bf16x4v*)&out[base] = o;
}

__global__ void __launch_bounds__(256) ln_f32_kernel(
    const bf16_t* __restrict__ pre, const float* __restrict__ g,
    const float* __restrict__ bt, float* __restrict__ out)
{
  const int r = blockIdx.x, tid = threadIdx.x;
  const long base = (long)r * EE + tid * 4;
  const bf16x4v pv = *(const bf16x4v*)&pre[base];
  float4 v = make_float4((float)pv[0], (float)pv[1], (float)pv[2], (float)pv[3]);
  float mu, rs;
  ln_reduce4(v, tid, mu, rs);
  const float4 gv = *(const float4*)&g[tid * 4];
  const float4 bv = *(const float4*)&bt[tid * 4];
  float4 o;
  o.x = (v.x - mu) * rs * gv.x + bv.x;
  o.y = (v.y - mu) * rs * gv.y + bv.y;
  o.z = (v.z - mu) * rs * gv.z + bv.z;
  o.w = (v.w - mu) * rs * gv.w + bv.w;
  *(float4*)&out[base] = o;
}

// ---------------------------------------------------------------------------
extern "C" void kernel_launch(void* const* d_in, const int* in_sizes, int n_in,
                              void* d_out, int out_size, void* d_ws, size_t ws_size,
                              hipStream_t stream)
{
  (void)in_sizes; (void)n_in; (void)out_size; (void)ws_size;
  const float* x     = (const float*)d_in[0];
  const float* Wq    = (const float*)d_in[1];
  const float* Wk    = (const float*)d_in[2];
  const float* Wv    = (const float*)d_in[3];
  const float* Wo    = (const float*)d_in[4];
  const float* theta = (const float*)d_in[5];
  const float* Wcq   = (const float*)d_in[6];
  const float* ln1g  = (const float*)d_in[7];
  const float* ln1b  = (const float*)d_in[8];
  const float* W1    = (const float*)d_in[9];
  const float* b1    = (const float*)d_in[10];
  const float* W2    = (const float*)d_in[11];
  const float* b2    = (const float*)d_in[12];
  const float* ln2g  = (const float*)d_in[13];
  const float* ln2b  = (const float*)d_in[14];

  // workspace layout (lifetime-aliased)
  char* ws = (char*)d_ws;
  const size_t MB = 1ull << 20;
  bf16_t* xbf     = (bf16_t*)(ws + 0);          // 16MB: bf16(x), later x1
  bf16_t* QKV     = (bf16_t*)(ws + 16 * MB);    // 48MB: q|k|v
  bf16_t* preLN1  = (bf16_t*)(ws + 16 * MB);    // 16MB alias (QKV dead after attn)
  bf16_t* A2      = (bf16_t*)(ws + 64 * MB);    // 32MB: [ctx | qh]
  bf16_t* preLN2  = (bf16_t*)(ws + 64 * MB);    // alias (A2 dead after attn-out)
  bf16_t* H1      = (bf16_t*)(ws + 96 * MB);    // 64MB: FFN hidden
  bf16_t* BtQKV   = (bf16_t*)(ws + 160 * MB);   // 6MB
  bf16_t* Bt2     = (bf16_t*)(ws + 166 * MB);   // 4MB
  bf16_t* BtW1    = (bf16_t*)(ws + 170 * MB);   // 8MB
  bf16_t* BtW2    = (bf16_t*)(ws + 178 * MB);   // 8MB

  prep_x_kernel<<<4096, 256, 0, stream>>>(x, theta, xbf, A2);
  transpose_all_kernel<<<13312, dim3(32, 8), 0, stream>>>(
      Wq, Wk, Wv, Wo, Wcq, W1, W2, BtQKV, Bt2, BtW1, BtW2);

  // 1) QKV projection — 8-phase 256^2 (384 blocks)
  gemm8p<0><<<dim3(12, 32), 512, 0, stream>>>(xbf, BtQKV, QKV, 8192, 3072, 1024, nullptr);
  // 2) flash attention -> ctx (left half of A2)
  attn_kernel<<<dim3(64, 16), 256, 0, stream>>>(QKV, A2);
  // 3) fused attn-out: bf16( 0.5*([ctx|qh] @ [Wo;Wcq]) + x ) -> preLN1
  gemm128<1><<<dim3(8, 32), 512, 0, stream>>>(A2, Bt2, preLN1, 8192, 1024, 2048, nullptr, xbf);
  // 4) LN1 -> x1 (bf16, overwrites xbf)
  ln_bf16_kernel<<<8192, 256, 0, stream>>>(preLN1, ln1g, ln1b, xbf);
  // 5) FFN1: relu(x1@W1 + b1) -> H1 — 8-phase 256^2 (512 blocks)
  gemm8p<2><<<dim3(16, 32), 512, 0, stream>>>(xbf, BtW1, H1, 8192, 4096, 1024, b1);
  // 6) FFN2: bf16( H1@W2 + b2 + x1 ) -> preLN2
  gemm128<3><<<dim3(8, 32), 512, 0, stream>>>(H1, BtW2, preLN2, 8192, 1024, 4096, b2, xbf);
  // 7) LN2 -> output (f32)
  ln_f32_kernel<<<8192, 256, 0, stream>>>(preLN2, ln2g, ln2b, (float*)d_out);
}